// Round 1
// baseline (3864.270 us; speedup 1.0000x reference)
//
#include <hip/hip_runtime.h>
#include <cmath>

// ---------------- problem constants ----------------
#define FEAT  192
#define CINCH 384          // CIN
#define CGATE 768
#define BATCH 16
#define HH    64
#define WW    64
#define NP    (BATCH*HH*WW)   // 65536 flattened (b,y,w)
#define KI2S  768             // 384 ic * 2 live taps
#define KS2S  576             // 192 feat * 3 taps

using bf16   = __bf16;
using bf16x8 = __attribute__((ext_vector_type(8))) __bf16;
using bf16x4 = __attribute__((ext_vector_type(4))) __bf16;
using f32x4  = __attribute__((ext_vector_type(4))) float;

// ============================================================
// Pack weights into bf16 GEMM operand layouts (A row-major, k contiguous).
//  Wp_i2s [768][768]: row = SHUFFLED channel c' = q*192+g*64+f  (orig c = g*256+q*64+f)
//        k<384: tap0 (input w-1), full.  k>=384: tap1 (center), masked og>=ig.
//  Wp_s2s [768][576]: k = t*192 + f  (so im2col patch rows are [h(w-1)|h(w)|h(w+1)])
//  Wp_skip[384][192]: masked 1x1.
// ============================================================
__global__ void pack_weights(const float* __restrict__ wi, const float* __restrict__ ws,
                             const float* __restrict__ wk,
                             bf16* __restrict__ WpA, bf16* __restrict__ WpS,
                             bf16* __restrict__ WpK) {
    int tid = blockIdx.x * 256 + threadIdx.x;
    int stride = gridDim.x * 256;
    for (int idx = tid; idx < CGATE * KI2S; idx += stride) {
        int cp = idx / KI2S, k = idx % KI2S;
        int q = cp / 192, r = cp % 192, g = r / 64, f = r % 64;
        int c = g * 256 + q * 64 + f;             // original (pre-shuffle) out channel
        float v;
        if (k < CINCH) {
            v = wi[(c * CINCH + k) * 3 + 0];      // tap0: full
        } else {
            int ic = k - CINCH;                   // tap1: causal group mask (og = c/256 = g)
            v = (g >= ic / 128) ? wi[(c * CINCH + ic) * 3 + 1] : 0.f;
        }
        WpA[idx] = (bf16)v;
    }
    for (int idx = tid; idx < CGATE * KS2S; idx += stride) {
        int oc = idx / KS2S, k = idx % KS2S;
        int t = k / FEAT, f = k % FEAT;
        WpS[idx] = (bf16)ws[(oc * FEAT + f) * 3 + t];   // no mask on s2s
    }
    for (int idx = tid; idx < CINCH * FEAT; idx += stride) {
        int co = idx / FEAT, f = idx % FEAT;
        WpK[idx] = (co / 128 >= f / 64) ? (bf16)wk[idx] : (bf16)0.f;
    }
}

// ============================================================
// Pack x (fp32 NCHW) -> Xp bf16 [p=(b,y,w)][k=768]  (B^T layout, k contiguous)
//   k<384 : x[b,k,y,w-1] (0 at w==0);  k>=384 : x[b,k-384,y,w]
// ============================================================
__global__ void pack_x(const float* __restrict__ x, bf16* __restrict__ Xp) {
    __shared__ float tile[64][65];
    int b = blockIdx.x >> 6, y = blockIdx.x & 63;
    const float* xb = x + ((size_t)b * CINCH * HH + y) * WW;      // + ic*4096 + w
    bf16* Xrow = Xp + ((size_t)b * HH * WW + (size_t)y * WW) * KI2S;
    for (int ic0 = 0; ic0 < CINCH; ic0 += 64) {
        for (int rep = 0; rep < 16; ++rep) {
            int idx = rep * 256 + threadIdx.x;
            int i = idx >> 6, w = idx & 63;
            tile[i][w] = xb[(size_t)(ic0 + i) * (HH * WW) + w];   // coalesced in w
        }
        __syncthreads();
        for (int rep = 0; rep < 16; ++rep) {
            int idx = rep * 256 + threadIdx.x;
            int w = idx >> 6, i = idx & 63;
            Xrow[(size_t)w * KI2S + CINCH + ic0 + i] = (bf16)tile[i][w];
            Xrow[(size_t)w * KI2S + ic0 + i] = (w == 0) ? (bf16)0.f : (bf16)tile[i][w - 1];
        }
        __syncthreads();
    }
}

// ============================================================
// i2s GEMM: Hbuf[c'][p] = sum_k WpA[c'][k] * Xp[p][k]   (M=768,N=65536,K=768)
// 128x128 tile, 256 thr (4 waves, each 64x64), BK=64, xor-swizzled LDS.
// ============================================================
__global__ __launch_bounds__(256) void gemm_i2s(const bf16* __restrict__ A,
                                                const bf16* __restrict__ B,
                                                bf16* __restrict__ Hout) {
    __shared__ __align__(16) bf16 As[128 * 64];
    __shared__ __align__(16) bf16 Bs[128 * 64];
    const int m0 = blockIdx.y * 128;
    const int p0 = blockIdx.x * 128;
    const int tid = threadIdx.x;
    const int lane = tid & 63, wid = tid >> 6;
    const int quad = lane >> 4, col = lane & 15;
    const int mhalf = (wid & 1) * 64, nhalf = (wid >> 1) * 64;
    f32x4 acc[4][4] = {};
    for (int k0 = 0; k0 < KI2S; k0 += 64) {
        for (int r = 0; r < 4; ++r) {           // stage 16KB A + 16KB B, swizzled
            int L = r * 256 + tid;              // 16B chunk id, 0..1023
            int row = L >> 3, slot = L & 7;
            int c = slot ^ (row & 7);
            ((uint4*)As)[L] = *(const uint4*)(&A[(size_t)(m0 + row) * KI2S + k0 + c * 8]);
            ((uint4*)Bs)[L] = *(const uint4*)(&B[(size_t)(p0 + row) * KI2S + k0 + c * 8]);
        }
        __syncthreads();
        for (int kk = 0; kk < 2; ++kk) {
            bf16x8 af[4], bfv[4];
            for (int mt = 0; mt < 4; ++mt) {
                int row = mhalf + mt * 16 + col;
                int slot = (kk * 4 + quad) ^ (row & 7);
                af[mt] = *(const bf16x8*)(&As[row * 64 + slot * 8]);
            }
            for (int nt = 0; nt < 4; ++nt) {
                int row = nhalf + nt * 16 + col;
                int slot = (kk * 4 + quad) ^ (row & 7);
                bfv[nt] = *(const bf16x8*)(&Bs[row * 64 + slot * 8]);
            }
            for (int mt = 0; mt < 4; ++mt)
                for (int nt = 0; nt < 4; ++nt)
                    acc[mt][nt] = __builtin_amdgcn_mfma_f32_16x16x32_bf16(
                        af[mt], bfv[nt], acc[mt][nt], 0, 0, 0);
        }
        __syncthreads();
    }
    for (int mt = 0; mt < 4; ++mt)
        for (int nt = 0; nt < 4; ++nt) {
            int m = m0 + mhalf + mt * 16 + quad * 4;
            int p = p0 + nhalf + nt * 16 + col;
            for (int r = 0; r < 4; ++r)
                Hout[(size_t)(m + r) * NP + p] = (bf16)acc[mt][nt][r];
        }
}

// ============================================================
// Row scan: 16 blocks (one per batch), 768 threads = 12 waves.
// Wave wid owns f' tile [wid*16, wid*16+16) for ALL 4 gates -> gates combine in-lane.
// _h lives in LDS [w+1][f] bf16, row stride 200 (halo rows 0 and 65 stay zero).
// Fused per-row: s2s MFMA + h_row add + LSTM update + masked 1x1 skip + residual out.
// ============================================================
__global__ __launch_bounds__(768, 3) void scan_kernel(
    const bf16* __restrict__ Hbuf,   // [768][65536]
    const bf16* __restrict__ Ws2s,   // [768][576]
    const bf16* __restrict__ Wskip,  // [384][192]
    const float* __restrict__ x,
    const float* __restrict__ b_skip,
    float* __restrict__ out) {
    __shared__ __align__(16) bf16 hlds[66 * 200];
    const int b = blockIdx.x;
    const int tid = threadIdx.x;
    const int lane = tid & 63, wid = tid >> 6;
    const int quad = lane >> 4, col = lane & 15;
    const int fp0 = wid * 16;

    for (int i = tid; i < 66 * 200; i += 768) hlds[i] = (bf16)0.f;
    __syncthreads();

    float cstate[4][4] = {};   // [nt][r] persistent cell state
    for (int y = 0; y < HH; ++y) {
        // ---- phase A: s = W_s2s * im2col(_h) ----
        f32x4 acc[4][4] = {};  // [gate q][nt]
        for (int kc = 0; kc < 18; ++kc) {
            int k0 = kc * 32 + quad * 8;
            int t = k0 / FEAT, f = k0 % FEAT;
            bf16x8 bfr[4];
            for (int nt = 0; nt < 4; ++nt) {
                int w = nt * 16 + col;
                bfr[nt] = *(const bf16x8*)(&hlds[(w + t) * 200 + f]);
            }
            for (int q = 0; q < 4; ++q) {
                bf16x8 afr = *(const bf16x8*)(
                    &Ws2s[(size_t)(q * FEAT + fp0 + col) * KS2S + k0]);
                for (int nt = 0; nt < 4; ++nt)
                    acc[q][nt] = __builtin_amdgcn_mfma_f32_16x16x32_bf16(
                        afr, bfr[nt], acc[q][nt], 0, 0, 0);
            }
        }
        __syncthreads();   // all hlds reads done before rewrite

        // ---- gates + cell update + write _h to LDS ----
        const size_t prow = (size_t)b * HH * WW + (size_t)y * WW;
        for (int nt = 0; nt < 4; ++nt) {
            int w = nt * 16 + col;
            bf16x4 hv;
            for (int r = 0; r < 4; ++r) {
                int fe = fp0 + quad * 4 + r;
                float so = acc[0][nt][r] + (float)Hbuf[(size_t)(0 * FEAT + fe) * NP + prow + w];
                float sf = acc[1][nt][r] + (float)Hbuf[(size_t)(1 * FEAT + fe) * NP + prow + w];
                float si = acc[2][nt][r] + (float)Hbuf[(size_t)(2 * FEAT + fe) * NP + prow + w];
                float sg = acc[3][nt][r] + (float)Hbuf[(size_t)(3 * FEAT + fe) * NP + prow + w];
                float go = 1.f / (1.f + __expf(-so));
                float gf = 1.f / (1.f + __expf(-sf));
                float gi = 1.f / (1.f + __expf(-si));
                float gg = 1.f / (1.f + __expf(-sg));
                float cc = gf * cstate[nt][r] + gi * gg;
                cstate[nt][r] = cc;
                hv[r] = (bf16)(go * tanhf(cc));
            }
            *(bf16x4*)(&hlds[(w + 1) * 200 + fp0 + quad * 4]) = hv;
        }
        __syncthreads();   // _h(y) visible

        // ---- phase B: skip = Wskip * _h ; out = x + b_skip + skip ----
        f32x4 acc2[2][4] = {};
        for (int kc = 0; kc < 6; ++kc) {
            int k0 = kc * 32 + quad * 8;
            bf16x8 bfr[4];
            for (int nt = 0; nt < 4; ++nt) {
                int w = nt * 16 + col;
                bfr[nt] = *(const bf16x8*)(&hlds[(w + 1) * 200 + k0]);
            }
            for (int mt = 0; mt < 2; ++mt) {
                bf16x8 afr = *(const bf16x8*)(
                    &Wskip[(size_t)(wid * 32 + mt * 16 + col) * FEAT + k0]);
                for (int nt = 0; nt < 4; ++nt)
                    acc2[mt][nt] = __builtin_amdgcn_mfma_f32_16x16x32_bf16(
                        afr, bfr[nt], acc2[mt][nt], 0, 0, 0);
            }
        }
        for (int mt = 0; mt < 2; ++mt)
            for (int r = 0; r < 4; ++r) {
                int co = wid * 32 + mt * 16 + quad * 4 + r;
                float bs = b_skip[co];
                for (int nt = 0; nt < 4; ++nt) {
                    int w = nt * 16 + col;
                    size_t xi = ((size_t)(b * CINCH + co) * HH + y) * WW + w;
                    out[xi] = x[xi] + bs + acc2[mt][nt][r];
                }
            }
        // no barrier needed here: next phase A only READS hlds before its own barrier
    }
}

// ============================================================
extern "C" void kernel_launch(void* const* d_in, const int* in_sizes, int n_in,
                              void* d_out, int out_size, void* d_ws, size_t ws_size,
                              hipStream_t stream) {
    const float* x      = (const float*)d_in[0];
    const float* w_i2s  = (const float*)d_in[1];
    const float* w_s2s  = (const float*)d_in[2];
    const float* w_skip = (const float*)d_in[3];
    const float* b_skip = (const float*)d_in[4];
    float* out = (float*)d_out;

    char* ws = (char*)d_ws;
    const size_t HBUF_B = (size_t)CGATE * NP * 2;        // 100,663,296
    bf16* Hbuf = (bf16*)ws;
    bf16* WpA  = (bf16*)(ws + HBUF_B);
    bf16* WpS  = (bf16*)(ws + HBUF_B + (size_t)CGATE * KI2S * 2);
    bf16* WpK  = (bf16*)(ws + HBUF_B + (size_t)CGATE * KI2S * 2 + (size_t)CGATE * KS2S * 2);
    bf16* Xp   = (bf16*)d_out;   // reuse d_out as im2col scratch (exactly 100,663,296 B);
                                 // dead before scan_kernel writes out.

    pack_weights<<<256, 256, 0, stream>>>(w_i2s, w_s2s, w_skip, WpA, WpS, WpK);
    pack_x<<<BATCH * HH, 256, 0, stream>>>(x, Xp);
    dim3 g3(NP / 128, CGATE / 128);
    gemm_i2s<<<g3, 256, 0, stream>>>(WpA, Xp, Hbuf);
    scan_kernel<<<BATCH, 768, 0, stream>>>(Hbuf, WpS, WpK, x, b_skip, out);
}

// Round 2
// 2422.761 us; speedup vs baseline: 1.5950x; 1.5950x over previous
//
#include <hip/hip_runtime.h>
#include <hip/hip_cooperative_groups.h>
#include <cmath>

// ---------------- problem constants ----------------
#define FEAT  192
#define CINCH 384          // CIN
#define CGATE 768
#define BATCH 16
#define HH    64
#define WW    64
#define NP    (BATCH*HH*WW)   // 65536 flattened (b,y,w)
#define KI2S  768             // 384 ic * 2 live taps
#define KS2S  576             // 192 feat * 3 taps
#define NBLK  192             // scan blocks: 16 batches x 12 f-chunks

using bf16   = __bf16;
using bf16x8 = __attribute__((ext_vector_type(8))) __bf16;
using bf16x4 = __attribute__((ext_vector_type(4))) __bf16;
using f32x4  = __attribute__((ext_vector_type(4))) float;

// ============================================================
// Pack weights into bf16 GEMM operand layouts (A row-major, k contiguous).
//  Wp_i2s [768][768]: row = SHUFFLED channel c' = q*192+g*64+f  (orig c = g*256+q*64+f)
//  Wp_s2s [768][576]: k = t*192 + f
//  Wp_skip[384][192]: masked 1x1.
// ============================================================
__global__ void pack_weights(const float* __restrict__ wi, const float* __restrict__ ws,
                             const float* __restrict__ wk,
                             bf16* __restrict__ WpA, bf16* __restrict__ WpS,
                             bf16* __restrict__ WpK) {
    int tid = blockIdx.x * 256 + threadIdx.x;
    int stride = gridDim.x * 256;
    for (int idx = tid; idx < CGATE * KI2S; idx += stride) {
        int cp = idx / KI2S, k = idx % KI2S;
        int q = cp / 192, r = cp % 192, g = r / 64, f = r % 64;
        int c = g * 256 + q * 64 + f;             // original (pre-shuffle) out channel
        float v;
        if (k < CINCH) {
            v = wi[(c * CINCH + k) * 3 + 0];      // tap0: full
        } else {
            int ic = k - CINCH;                   // tap1: causal group mask
            v = (g >= ic / 128) ? wi[(c * CINCH + ic) * 3 + 1] : 0.f;
        }
        WpA[idx] = (bf16)v;
    }
    for (int idx = tid; idx < CGATE * KS2S; idx += stride) {
        int oc = idx / KS2S, k = idx % KS2S;
        int t = k / FEAT, f = k % FEAT;
        WpS[idx] = (bf16)ws[(oc * FEAT + f) * 3 + t];
    }
    for (int idx = tid; idx < CINCH * FEAT; idx += stride) {
        int co = idx / FEAT, f = idx % FEAT;
        WpK[idx] = (co / 128 >= f / 64) ? (bf16)wk[idx] : (bf16)0.f;
    }
}

// ============================================================
// Pack x (fp32 NCHW) -> Xp bf16 [p=(b,y,w)][k=768]
// ============================================================
__global__ void pack_x(const float* __restrict__ x, bf16* __restrict__ Xp) {
    __shared__ float tile[64][65];
    int b = blockIdx.x >> 6, y = blockIdx.x & 63;
    const float* xb = x + ((size_t)b * CINCH * HH + y) * WW;
    bf16* Xrow = Xp + ((size_t)b * HH * WW + (size_t)y * WW) * KI2S;
    for (int ic0 = 0; ic0 < CINCH; ic0 += 64) {
        for (int rep = 0; rep < 16; ++rep) {
            int idx = rep * 256 + threadIdx.x;
            int i = idx >> 6, w = idx & 63;
            tile[i][w] = xb[(size_t)(ic0 + i) * (HH * WW) + w];
        }
        __syncthreads();
        for (int rep = 0; rep < 16; ++rep) {
            int idx = rep * 256 + threadIdx.x;
            int w = idx >> 6, i = idx & 63;
            Xrow[(size_t)w * KI2S + CINCH + ic0 + i] = (bf16)tile[i][w];
            Xrow[(size_t)w * KI2S + ic0 + i] = (w == 0) ? (bf16)0.f : (bf16)tile[i][w - 1];
        }
        __syncthreads();
    }
}

// ============================================================
// i2s GEMM: Hbuf[c'][p] = sum_k WpA[c'][k] * Xp[p][k]  (unchanged, verified)
// ============================================================
__global__ __launch_bounds__(256) void gemm_i2s(const bf16* __restrict__ A,
                                                const bf16* __restrict__ B,
                                                bf16* __restrict__ Hout) {
    __shared__ __align__(16) bf16 As[128 * 64];
    __shared__ __align__(16) bf16 Bs[128 * 64];
    const int m0 = blockIdx.y * 128;
    const int p0 = blockIdx.x * 128;
    const int tid = threadIdx.x;
    const int lane = tid & 63, wid = tid >> 6;
    const int quad = lane >> 4, col = lane & 15;
    const int mhalf = (wid & 1) * 64, nhalf = (wid >> 1) * 64;
    f32x4 acc[4][4] = {};
    for (int k0 = 0; k0 < KI2S; k0 += 64) {
        for (int r = 0; r < 4; ++r) {
            int L = r * 256 + tid;
            int row = L >> 3, slot = L & 7;
            int c = slot ^ (row & 7);
            ((uint4*)As)[L] = *(const uint4*)(&A[(size_t)(m0 + row) * KI2S + k0 + c * 8]);
            ((uint4*)Bs)[L] = *(const uint4*)(&B[(size_t)(p0 + row) * KI2S + k0 + c * 8]);
        }
        __syncthreads();
        for (int kk = 0; kk < 2; ++kk) {
            bf16x8 af[4], bfv[4];
            for (int mt = 0; mt < 4; ++mt) {
                int row = mhalf + mt * 16 + col;
                int slot = (kk * 4 + quad) ^ (row & 7);
                af[mt] = *(const bf16x8*)(&As[row * 64 + slot * 8]);
            }
            for (int nt = 0; nt < 4; ++nt) {
                int row = nhalf + nt * 16 + col;
                int slot = (kk * 4 + quad) ^ (row & 7);
                bfv[nt] = *(const bf16x8*)(&Bs[row * 64 + slot * 8]);
            }
            for (int mt = 0; mt < 4; ++mt)
                for (int nt = 0; nt < 4; ++nt)
                    acc[mt][nt] = __builtin_amdgcn_mfma_f32_16x16x32_bf16(
                        af[mt], bfv[nt], acc[mt][nt], 0, 0, 0);
        }
        __syncthreads();
    }
    for (int mt = 0; mt < 4; ++mt)
        for (int nt = 0; nt < 4; ++nt) {
            int m = m0 + mhalf + mt * 16 + quad * 4;
            int p = p0 + nhalf + nt * 16 + col;
            for (int r = 0; r < 4; ++r)
                Hout[(size_t)(m + r) * NP + p] = (bf16)acc[mt][nt][r];
        }
}

// ============================================================
// Cooperative row scan: 192 blocks = 16 batches x 12 feature-chunks(16f).
// 256 thr = 4 waves; wave wid owns features [16j+4*wid, +4) x 4 gates as ONE
// m-tile (A row c' = (m&3)*192 + 16j + wid*4 + (m>>2)), so D reg r = gate q
// and all 4 gates of a feature land in one thread. s2s A-slice (72 VGPR) and
// skip A-slice (24 VGPR) are register-persistent across all rows.
// h triple-buffered in global hg[3][16][66][192] (halos w'=0,65 stay zero);
// one grid.sync per row.
// ============================================================
__global__ __launch_bounds__(256) void scan_kernel(
    const bf16* __restrict__ Hbuf,   // [768][65536]
    const bf16* __restrict__ Ws2s,   // [768][576]
    const bf16* __restrict__ Wskip,  // [384][192]
    const float* __restrict__ x,
    const float* __restrict__ b_skip,
    float* __restrict__ out,
    bf16* __restrict__ hg) {         // [3][16][66*192]
    cooperative_groups::grid_group grid = cooperative_groups::this_grid();
    __shared__ __align__(16) bf16 hlds[66 * 200];
    const int bid = blockIdx.x;
    const int b = bid / 12, j = bid % 12;
    const int tid = threadIdx.x, lane = tid & 63, wid = tid >> 6;
    const int quad = lane >> 4, col = lane & 15;

    // zero hg (all 3 buffers; halo rows rely on this)
    {
        const int total = 3 * 16 * 66 * 192 / 2;   // dwords
        for (int i = bid * 256 + tid; i < total; i += NBLK * 256)
            ((unsigned*)hg)[i] = 0u;
    }
    // persistent A fragments
    bf16x8 Ag[18];
    {
        int f = 16 * j + wid * 4 + (col >> 2), q = col & 3;
        const bf16* Arow = Ws2s + (size_t)(q * 192 + f) * KS2S + quad * 8;
        for (int kc = 0; kc < 18; ++kc) Ag[kc] = *(const bf16x8*)(Arow + kc * 32);
    }
    bf16x8 Ak[6];
    const int mtk = wid & 1, ntk0 = (wid >> 1) * 2;
    {
        int co = 32 * j + mtk * 16 + col;
        const bf16* Krow = Wskip + (size_t)co * FEAT + quad * 8;
        for (int kc = 0; kc < 6; ++kc) Ak[kc] = *(const bf16x8*)(Krow + kc * 32);
    }
    const int fmine = 16 * j + wid * 4 + quad;
    float cstate[4] = {0.f, 0.f, 0.f, 0.f};
    grid.sync();

    const size_t pbase = (size_t)b * HH * WW;
    for (int y = 0; y <= 64; ++y) {
        // ---- stage h(y-1) = hg[(y+2)%3][b] -> LDS (coalesced b128) ----
        const bf16* src = hg + ((size_t)((y + 2) % 3) * 16 + b) * (66 * 192);
        for (int c = tid; c < 1584; c += 256) {
            int w = c / 24, fo = (c % 24) * 8;
            *(bf16x8*)(&hlds[w * 200 + fo]) = *(const bf16x8*)(src + w * 192 + fo);
        }
        __syncthreads();

        // ---- skip GEMM + residual out for row y-1 (reads staged h(y-1)) ----
        if (y > 0) {
            const int ym = y - 1;
            f32x4 acc2[2] = {};
            for (int kc = 0; kc < 6; ++kc)
                for (int i = 0; i < 2; ++i) {
                    int w = (ntk0 + i) * 16 + col;
                    bf16x8 bfr = *(const bf16x8*)(&hlds[(w + 1) * 200 + kc * 32 + quad * 8]);
                    acc2[i] = __builtin_amdgcn_mfma_f32_16x16x32_bf16(Ak[kc], bfr, acc2[i], 0, 0, 0);
                }
            for (int r = 0; r < 4; ++r) {
                int co = 32 * j + mtk * 16 + quad * 4 + r;
                float bs = b_skip[co];
                for (int i = 0; i < 2; ++i) {
                    int w = (ntk0 + i) * 16 + col;
                    size_t xi = ((size_t)(b * CINCH + co) * HH + ym) * WW + w;
                    out[xi] = x[xi] + bs + acc2[i][r];
                }
            }
        }

        if (y < 64) {
            // prefetch Hbuf gate biases (global, overlap with MFMA below)
            const size_t prow = pbase + (size_t)y * WW;
            float hadd[4][4];
            for (int nt = 0; nt < 4; ++nt) {
                int w = nt * 16 + col;
                for (int r = 0; r < 4; ++r)
                    hadd[nt][r] = (float)Hbuf[(size_t)(r * FEAT + fmine) * NP + prow + w];
            }
            // gates GEMM: s = Ws2s_slice * im2col(h(y-1))
            f32x4 acc[4] = {};
            for (int kc = 0; kc < 18; ++kc) {
                int k0 = kc * 32 + quad * 8;
                int t = k0 / FEAT, f = k0 % FEAT;
                for (int nt = 0; nt < 4; ++nt) {
                    int w = nt * 16 + col;
                    bf16x8 bfr = *(const bf16x8*)(&hlds[(w + t) * 200 + f]);
                    acc[nt] = __builtin_amdgcn_mfma_f32_16x16x32_bf16(Ag[kc], bfr, acc[nt], 0, 0, 0);
                }
            }
            __syncthreads();   // all hlds reads (skip + gates) done before rewrite

            // LSTM update: reg r = gate q (o,f,i,g); one feature per thread
            for (int nt = 0; nt < 4; ++nt) {
                int w = nt * 16 + col;
                float so = acc[nt][0] + hadd[nt][0];
                float sf = acc[nt][1] + hadd[nt][1];
                float si = acc[nt][2] + hadd[nt][2];
                float sg = acc[nt][3] + hadd[nt][3];
                float go = 1.f / (1.f + __expf(-so));
                float gf = 1.f / (1.f + __expf(-sf));
                float gi = 1.f / (1.f + __expf(-si));
                float gg = 1.f / (1.f + __expf(-sg));
                float cc = gf * cstate[nt] + gi * gg;
                cstate[nt] = cc;
                hlds[(w + 1) * 200 + fmine] = (bf16)(go * tanhf(cc));
            }
            __syncthreads();
            // publish own 16-feature slice of h(y) to hg[y%3][b]
            bf16* dst = hg + ((size_t)(y % 3) * 16 + b) * (66 * 192);
            {
                int w = 1 + (tid >> 2), fo = 16 * j + (tid & 3) * 4;
                *(bf16x4*)(dst + w * 192 + fo) = *(const bf16x4*)(&hlds[w * 200 + fo]);
            }
            grid.sync();
        }
    }
}

// ============================================================
extern "C" void kernel_launch(void* const* d_in, const int* in_sizes, int n_in,
                              void* d_out, int out_size, void* d_ws, size_t ws_size,
                              hipStream_t stream) {
    const float* x      = (const float*)d_in[0];
    const float* w_i2s  = (const float*)d_in[1];
    const float* w_s2s  = (const float*)d_in[2];
    const float* w_skip = (const float*)d_in[3];
    const float* b_skip = (const float*)d_in[4];
    float* out = (float*)d_out;

    char* ws = (char*)d_ws;
    const size_t HBUF_B = (size_t)CGATE * NP * 2;        // 100,663,296
    bf16* Hbuf = (bf16*)ws;
    bf16* WpA  = (bf16*)(ws + HBUF_B);
    bf16* WpS  = (bf16*)(ws + HBUF_B + (size_t)CGATE * KI2S * 2);
    bf16* WpK  = (bf16*)(ws + HBUF_B + (size_t)CGATE * KI2S * 2 + (size_t)CGATE * KS2S * 2);
    bf16* hg   = (bf16*)(ws + HBUF_B + (size_t)CGATE * KI2S * 2 + (size_t)CGATE * KS2S * 2
                            + (size_t)CINCH * FEAT * 2);   // 3*16*66*192 bf16 = 1.2 MB
    bf16* Xp   = (bf16*)d_out;   // im2col scratch in d_out; dead before scan writes out

    pack_weights<<<256, 256, 0, stream>>>(w_i2s, w_s2s, w_skip, WpA, WpS, WpK);
    pack_x<<<BATCH * HH, 256, 0, stream>>>(x, Xp);
    dim3 g3(NP / 128, CGATE / 128);
    gemm_i2s<<<g3, 256, 0, stream>>>(WpA, Xp, Hbuf);

    void* args[] = { (void*)&Hbuf, (void*)&WpS, (void*)&WpK,
                     (void*)&x, (void*)&b_skip, (void*)&out, (void*)&hg };
    hipLaunchCooperativeKernel((const void*)scan_kernel, dim3(NBLK), dim3(256),
                               args, 0, stream);
}

// Round 3
// 1190.385 us; speedup vs baseline: 3.2462x; 2.0353x over previous
//
#include <hip/hip_runtime.h>
#include <hip/hip_cooperative_groups.h>
#include <cmath>

// ---------------- problem constants ----------------
#define FEAT  192
#define CINCH 384          // CIN
#define CGATE 768
#define BATCH 16
#define HH    64
#define WW    64
#define NP    (BATCH*HH*WW)   // 65536 flattened (b,y,w)
#define KI2S  768             // 384 ic * 2 live taps
#define KS2S  576             // 192 feat * 3 taps
#define NBLK  192             // scan blocks: 16 batches x 12 f-chunks

using bf16   = __bf16;
using bf16x8 = __attribute__((ext_vector_type(8))) __bf16;
using bf16x4 = __attribute__((ext_vector_type(4))) __bf16;
using f32x4  = __attribute__((ext_vector_type(4))) float;

// ============================================================
// Pack weights into bf16 GEMM operand layouts (A row-major, k contiguous).
// ============================================================
__global__ void pack_weights(const float* __restrict__ wi, const float* __restrict__ ws,
                             const float* __restrict__ wk,
                             bf16* __restrict__ WpA, bf16* __restrict__ WpS,
                             bf16* __restrict__ WpK) {
    int tid = blockIdx.x * 256 + threadIdx.x;
    int stride = gridDim.x * 256;
    for (int idx = tid; idx < CGATE * KI2S; idx += stride) {
        int cp = idx / KI2S, k = idx % KI2S;
        int q = cp / 192, r = cp % 192, g = r / 64, f = r % 64;
        int c = g * 256 + q * 64 + f;             // original (pre-shuffle) out channel
        float v;
        if (k < CINCH) {
            v = wi[(c * CINCH + k) * 3 + 0];      // tap0: full
        } else {
            int ic = k - CINCH;                   // tap1: causal group mask
            v = (g >= ic / 128) ? wi[(c * CINCH + ic) * 3 + 1] : 0.f;
        }
        WpA[idx] = (bf16)v;
    }
    for (int idx = tid; idx < CGATE * KS2S; idx += stride) {
        int oc = idx / KS2S, k = idx % KS2S;
        int t = k / FEAT, f = k % FEAT;
        WpS[idx] = (bf16)ws[(oc * FEAT + f) * 3 + t];
    }
    for (int idx = tid; idx < CINCH * FEAT; idx += stride) {
        int co = idx / FEAT, f = idx % FEAT;
        WpK[idx] = (co / 128 >= f / 64) ? (bf16)wk[idx] : (bf16)0.f;
    }
}

// ============================================================
// Pack x (fp32 NCHW) -> Xp bf16 [p=(b,y,w)][k=768]
// ============================================================
__global__ void pack_x(const float* __restrict__ x, bf16* __restrict__ Xp) {
    __shared__ float tile[64][65];
    int b = blockIdx.x >> 6, y = blockIdx.x & 63;
    const float* xb = x + ((size_t)b * CINCH * HH + y) * WW;
    bf16* Xrow = Xp + ((size_t)b * HH * WW + (size_t)y * WW) * KI2S;
    for (int ic0 = 0; ic0 < CINCH; ic0 += 64) {
        for (int rep = 0; rep < 16; ++rep) {
            int idx = rep * 256 + threadIdx.x;
            int i = idx >> 6, w = idx & 63;
            tile[i][w] = xb[(size_t)(ic0 + i) * (HH * WW) + w];
        }
        __syncthreads();
        for (int rep = 0; rep < 16; ++rep) {
            int idx = rep * 256 + threadIdx.x;
            int w = idx >> 6, i = idx & 63;
            Xrow[(size_t)w * KI2S + CINCH + ic0 + i] = (bf16)tile[i][w];
            Xrow[(size_t)w * KI2S + ic0 + i] = (w == 0) ? (bf16)0.f : (bf16)tile[i][w - 1];
        }
        __syncthreads();
    }
}

// ============================================================
// i2s GEMM: Hbuf[c'][p] = sum_k WpA[c'][k] * Xp[p][k]  (unchanged, verified)
// ============================================================
__global__ __launch_bounds__(256) void gemm_i2s(const bf16* __restrict__ A,
                                                const bf16* __restrict__ B,
                                                bf16* __restrict__ Hout) {
    __shared__ __align__(16) bf16 As[128 * 64];
    __shared__ __align__(16) bf16 Bs[128 * 64];
    const int m0 = blockIdx.y * 128;
    const int p0 = blockIdx.x * 128;
    const int tid = threadIdx.x;
    const int lane = tid & 63, wid = tid >> 6;
    const int quad = lane >> 4, col = lane & 15;
    const int mhalf = (wid & 1) * 64, nhalf = (wid >> 1) * 64;
    f32x4 acc[4][4] = {};
    for (int k0 = 0; k0 < KI2S; k0 += 64) {
        for (int r = 0; r < 4; ++r) {
            int L = r * 256 + tid;
            int row = L >> 3, slot = L & 7;
            int c = slot ^ (row & 7);
            ((uint4*)As)[L] = *(const uint4*)(&A[(size_t)(m0 + row) * KI2S + k0 + c * 8]);
            ((uint4*)Bs)[L] = *(const uint4*)(&B[(size_t)(p0 + row) * KI2S + k0 + c * 8]);
        }
        __syncthreads();
        for (int kk = 0; kk < 2; ++kk) {
            bf16x8 af[4], bfv[4];
            for (int mt = 0; mt < 4; ++mt) {
                int row = mhalf + mt * 16 + col;
                int slot = (kk * 4 + quad) ^ (row & 7);
                af[mt] = *(const bf16x8*)(&As[row * 64 + slot * 8]);
            }
            for (int nt = 0; nt < 4; ++nt) {
                int row = nhalf + nt * 16 + col;
                int slot = (kk * 4 + quad) ^ (row & 7);
                bfv[nt] = *(const bf16x8*)(&Bs[row * 64 + slot * 8]);
            }
            for (int mt = 0; mt < 4; ++mt)
                for (int nt = 0; nt < 4; ++nt)
                    acc[mt][nt] = __builtin_amdgcn_mfma_f32_16x16x32_bf16(
                        af[mt], bfv[nt], acc[mt][nt], 0, 0, 0);
        }
        __syncthreads();
    }
    for (int mt = 0; mt < 4; ++mt)
        for (int nt = 0; nt < 4; ++nt) {
            int m = m0 + mhalf + mt * 16 + quad * 4;
            int p = p0 + nhalf + nt * 16 + col;
            for (int r = 0; r < 4; ++r)
                Hout[(size_t)(m + r) * NP + p] = (bf16)acc[mt][nt][r];
        }
}

// ============================================================
// Per-batch 12-block barrier: monotone counter, release on arrival,
// relaxed spin + one acquire, s_sleep to keep the SIMD free.
// Transitivity: __syncthreads makes all block threads' h-stores
// happen-before tid0's release; reader side acquire (wbl2/inv are
// XCD-wide) + __syncthreads covers all reader threads.
// ============================================================
__device__ __forceinline__ void batch_barrier(unsigned* cnt, int tid, unsigned target) {
    __syncthreads();
    if (tid == 0) {
        __hip_atomic_fetch_add(cnt, 1u, __ATOMIC_RELEASE, __HIP_MEMORY_SCOPE_AGENT);
        while (__hip_atomic_load(cnt, __ATOMIC_RELAXED, __HIP_MEMORY_SCOPE_AGENT) < target)
            __builtin_amdgcn_s_sleep(2);
        (void)__hip_atomic_load(cnt, __ATOMIC_ACQUIRE, __HIP_MEMORY_SCOPE_AGENT);
    }
    __syncthreads();
}

// ============================================================
// Cooperative row scan: 192 blocks = 16 batches x 12 feature-chunks(16f).
// bid swizzled so a batch's 12 blocks share bid%8 (likely same XCD).
// Per-row sync = per-batch 12-block barrier (batches fully independent).
// ============================================================
__global__ __launch_bounds__(256) void scan_kernel(
    const bf16* __restrict__ Hbuf,   // [768][65536]
    const bf16* __restrict__ Ws2s,   // [768][576]
    const bf16* __restrict__ Wskip,  // [384][192]
    const float* __restrict__ x,
    const float* __restrict__ b_skip,
    float* __restrict__ out,
    bf16* __restrict__ hg,           // [3][16][66*192]
    unsigned* __restrict__ cnt) {    // [16][32] padded counters
    cooperative_groups::grid_group grid = cooperative_groups::this_grid();
    __shared__ __align__(16) bf16 hlds[66 * 200];
    const int bid = blockIdx.x;
    const int b = (bid & 7) * 2 + (bid / 96);   // same-batch blocks share bid%8
    const int j = (bid >> 3) % 12;
    const int tid = threadIdx.x, lane = tid & 63, wid = tid >> 6;
    const int quad = lane >> 4, col = lane & 15;

    // zero hg (halo rows rely on this) + barrier counters
    {
        const int total = 3 * 16 * 66 * 192 / 2;   // dwords
        for (int i = bid * 256 + tid; i < total; i += NBLK * 256)
            ((unsigned*)hg)[i] = 0u;
        if (tid < 32) cnt[bid % 16 * 32 + tid] = 0u;
    }
    // persistent A fragments
    bf16x8 Ag[18];
    {
        int f = 16 * j + wid * 4 + (col >> 2), q = col & 3;
        const bf16* Arow = Ws2s + (size_t)(q * 192 + f) * KS2S + quad * 8;
        for (int kc = 0; kc < 18; ++kc) Ag[kc] = *(const bf16x8*)(Arow + kc * 32);
    }
    bf16x8 Ak[6];
    const int mtk = wid & 1, ntk0 = (wid >> 1) * 2;
    {
        int co = 32 * j + mtk * 16 + col;
        const bf16* Krow = Wskip + (size_t)co * FEAT + quad * 8;
        for (int kc = 0; kc < 6; ++kc) Ak[kc] = *(const bf16x8*)(Krow + kc * 32);
    }
    const int fmine = 16 * j + wid * 4 + quad;
    float cstate[4] = {0.f, 0.f, 0.f, 0.f};
    unsigned* mycnt = cnt + b * 32;
    grid.sync();   // init visibility only; per-row sync is per-batch below

    const size_t pbase = (size_t)b * HH * WW;
    for (int y = 0; y <= 64; ++y) {
        // ---- stage h(y-1) = hg[(y+2)%3][b] -> LDS (coalesced b128) ----
        const bf16* src = hg + ((size_t)((y + 2) % 3) * 16 + b) * (66 * 192);
        for (int c = tid; c < 1584; c += 256) {
            int w = c / 24, fo = (c % 24) * 8;
            *(bf16x8*)(&hlds[w * 200 + fo]) = *(const bf16x8*)(src + w * 192 + fo);
        }
        __syncthreads();

        // ---- skip GEMM + residual out for row y-1 ----
        if (y > 0) {
            const int ym = y - 1;
            f32x4 acc2[2] = {};
            for (int kc = 0; kc < 6; ++kc)
                for (int i = 0; i < 2; ++i) {
                    int w = (ntk0 + i) * 16 + col;
                    bf16x8 bfr = *(const bf16x8*)(&hlds[(w + 1) * 200 + kc * 32 + quad * 8]);
                    acc2[i] = __builtin_amdgcn_mfma_f32_16x16x32_bf16(Ak[kc], bfr, acc2[i], 0, 0, 0);
                }
            for (int r = 0; r < 4; ++r) {
                int co = 32 * j + mtk * 16 + quad * 4 + r;
                float bs = b_skip[co];
                for (int i = 0; i < 2; ++i) {
                    int w = (ntk0 + i) * 16 + col;
                    size_t xi = ((size_t)(b * CINCH + co) * HH + ym) * WW + w;
                    out[xi] = x[xi] + bs + acc2[i][r];
                }
            }
        }

        if (y < 64) {
            // prefetch Hbuf gate biases (overlap with MFMA below)
            const size_t prow = pbase + (size_t)y * WW;
            float hadd[4][4];
            for (int nt = 0; nt < 4; ++nt) {
                int w = nt * 16 + col;
                for (int r = 0; r < 4; ++r)
                    hadd[nt][r] = (float)Hbuf[(size_t)(r * FEAT + fmine) * NP + prow + w];
            }
            // gates GEMM: s = Ws2s_slice * im2col(h(y-1))
            f32x4 acc[4] = {};
            for (int kc = 0; kc < 18; ++kc) {
                int k0 = kc * 32 + quad * 8;
                int t = k0 / FEAT, f = k0 % FEAT;
                for (int nt = 0; nt < 4; ++nt) {
                    int w = nt * 16 + col;
                    bf16x8 bfr = *(const bf16x8*)(&hlds[(w + t) * 200 + f]);
                    acc[nt] = __builtin_amdgcn_mfma_f32_16x16x32_bf16(Ag[kc], bfr, acc[nt], 0, 0, 0);
                }
            }
            __syncthreads();   // all hlds reads (skip + gates) done before rewrite

            // LSTM update: reg r = gate q (o,f,i,g); one feature per thread
            for (int nt = 0; nt < 4; ++nt) {
                int w = nt * 16 + col;
                float so = acc[nt][0] + hadd[nt][0];
                float sf = acc[nt][1] + hadd[nt][1];
                float si = acc[nt][2] + hadd[nt][2];
                float sg = acc[nt][3] + hadd[nt][3];
                float go = 1.f / (1.f + __expf(-so));
                float gf = 1.f / (1.f + __expf(-sf));
                float gi = 1.f / (1.f + __expf(-si));
                float gg = 1.f / (1.f + __expf(-sg));
                float cc = gf * cstate[nt] + gi * gg;
                cstate[nt] = cc;
                hlds[(w + 1) * 200 + fmine] = (bf16)(go * tanhf(cc));
            }
            __syncthreads();
            // publish own 16-feature slice of h(y) to hg[y%3][b]
            bf16* dst = hg + ((size_t)(y % 3) * 16 + b) * (66 * 192);
            {
                int w = 1 + (tid >> 2), fo = 16 * j + (tid & 3) * 4;
                *(bf16x4*)(dst + w * 192 + fo) = *(const bf16x4*)(&hlds[w * 200 + fo]);
            }
            batch_barrier(mycnt, tid, 12u * (unsigned)(y + 1));
        }
    }
}

// ============================================================
extern "C" void kernel_launch(void* const* d_in, const int* in_sizes, int n_in,
                              void* d_out, int out_size, void* d_ws, size_t ws_size,
                              hipStream_t stream) {
    const float* x      = (const float*)d_in[0];
    const float* w_i2s  = (const float*)d_in[1];
    const float* w_s2s  = (const float*)d_in[2];
    const float* w_skip = (const float*)d_in[3];
    const float* b_skip = (const float*)d_in[4];
    float* out = (float*)d_out;

    char* ws = (char*)d_ws;
    const size_t HBUF_B = (size_t)CGATE * NP * 2;        // 100,663,296
    bf16* Hbuf = (bf16*)ws;
    size_t off = HBUF_B;
    bf16* WpA  = (bf16*)(ws + off); off += (size_t)CGATE * KI2S * 2;
    bf16* WpS  = (bf16*)(ws + off); off += (size_t)CGATE * KS2S * 2;
    bf16* WpK  = (bf16*)(ws + off); off += (size_t)CINCH * FEAT * 2;
    bf16* hg   = (bf16*)(ws + off); off += (size_t)3 * 16 * 66 * 192 * 2;
    unsigned* cnt = (unsigned*)(ws + off);               // 16*32 u32 = 2 KB
    bf16* Xp   = (bf16*)d_out;   // im2col scratch in d_out; dead before scan writes out

    pack_weights<<<256, 256, 0, stream>>>(w_i2s, w_s2s, w_skip, WpA, WpS, WpK);
    pack_x<<<BATCH * HH, 256, 0, stream>>>(x, Xp);
    dim3 g3(NP / 128, CGATE / 128);
    gemm_i2s<<<g3, 256, 0, stream>>>(WpA, Xp, Hbuf);

    void* args[] = { (void*)&Hbuf, (void*)&WpS, (void*)&WpK,
                     (void*)&x, (void*)&b_skip, (void*)&out, (void*)&hg, (void*)&cnt };
    hipLaunchCooperativeKernel((const void*)scan_kernel, dim3(NBLK), dim3(256),
                               args, 0, stream);
}